// Round 16
// baseline (561.019 us; speedup 1.0000x reference)
//
#include <hip/hip_runtime.h>
#include <hip/hip_bf16.h>
#include <float.h>
#include <math.h>

// ---------------- problem constants ----------------
#define BB 2
#define SS 1024
#define LL 767
#define TT 1536          // 2*(LL+1)
#define DD 256
#define HH 8
#define DHD 2048
#define INNER_ 16384
#define VV 25426
#define VPAD 25472
#define CLS_TOK 25426
#define MASK_TOKEN 25428
#define ROWS (BB*TT)     // 3072
#define SROWS (BB*SS)    // 2048

typedef __attribute__((ext_vector_type(8))) __bf16 bf16x8;
typedef __attribute__((ext_vector_type(4))) float f32x4;

__device__ __forceinline__ unsigned short f2bu(float f) {
    union { float f; unsigned u; } v; v.f = f;
    unsigned r = v.u + 0x7fff + ((v.u >> 16) & 1);
    return (unsigned short)(r >> 16);
}
__device__ __forceinline__ float bu2f(unsigned short u) {
    union { unsigned u; float f; } v; v.u = ((unsigned)u) << 16;
    return v.f;
}

__device__ __forceinline__ void gload16(const void* g, void* l) {
    __builtin_amdgcn_global_load_lds(
        (const __attribute__((address_space(1))) void*)g,
        (__attribute__((address_space(3))) void*)l, 16, 0, 0);
}

// ---------------- small helper kernels ----------------

__global__ __launch_bounds__(256) void embed_kernel(
    const int* __restrict__ t1, const int* __restrict__ t2,
    const float* __restrict__ emb, float* __restrict__ x,
    unsigned short* __restrict__ xb, unsigned char* __restrict__ tgt_pad)
{
    int t = blockIdx.x, b = blockIdx.y, d = threadIdx.x;
    int raw;
    if (t == 0)            raw = CLS_TOK;
    else if (t <= LL)      raw = t1[b * LL + (t - 1)];
    else if (t == LL + 1)  raw = CLS_TOK;
    else                   raw = t2[b * LL + (t - LL - 2)];
    int id = (raw == 0 || raw == MASK_TOKEN) ? MASK_TOKEN : raw;
    int i = d >> 1;
    float ang = (float)t * expf(-0.03597789208f * (float)(2 * i));
    float pe = (d & 1) ? cosf(ang) : sinf(ang);
    float val = 2.f * emb[(long long)id * DD + d] + pe;
    long long idx = ((long long)(b * TT + t)) * DD + d;
    x[idx] = val;
    xb[idx] = f2bu(val);
    if (d == 0) tgt_pad[b * TT + t] = (raw == 0) ? 1 : 0;
}

// src pad mask + rowmap in one launch (grid ROWS/256)
__global__ __launch_bounds__(256) void masks_kernel(
    const int* __restrict__ src, unsigned char* __restrict__ m, int* __restrict__ rm)
{
    int i = blockIdx.x * 256 + threadIdx.x;
    if (i < SROWS) m[i] = (src[i] == 0) ? 1 : 0;
    if (i < ROWS) {
        int b = i / TT, t = i % TT;
        rm[i] = (t == 0) ? -1 : (b * (TT - 1) + t - 1);
    }
}

__global__ __launch_bounds__(256) void copycls_kernel(
    const float* __restrict__ x, float* __restrict__ out2)
{
    int b = blockIdx.x, d = threadIdx.x;
    out2[b * DD + d] = x[(long long)b * TT * DD + d];
}

// vectorized f32 -> bf16 convert (4 elems/thread); n % 1024 == 0
__global__ __launch_bounds__(256) void conv_bf16v4(
    const float* __restrict__ in, unsigned short* __restrict__ out)
{
    size_t i = ((size_t)blockIdx.x * 256 + threadIdx.x) * 4;
    float4 v = *reinterpret_cast<const float4*>(in + i);
    ushort4 u;
    u.x = f2bu(v.x); u.y = f2bu(v.y); u.z = f2bu(v.z); u.w = f2bu(v.w);
    *reinterpret_cast<ushort4*>(out + i) = u;
}

// six weight matrices [DD][INNER_] f32 -> contiguous bf16 (one launch)
__global__ __launch_bounds__(256) void convW6(
    const float* __restrict__ w0, const float* __restrict__ w1,
    const float* __restrict__ w2, const float* __restrict__ w3,
    const float* __restrict__ w4, const float* __restrict__ w5,
    unsigned short* __restrict__ dst)
{
    int seg = blockIdx.y;
    const float* s = seg == 0 ? w0 : seg == 1 ? w1 : seg == 2 ? w2 :
                     seg == 3 ? w3 : seg == 4 ? w4 : w5;
    size_t i = ((size_t)blockIdx.x * 256 + threadIdx.x) * 4;
    float4 v = *reinterpret_cast<const float4*>(s + i);
    ushort4 u;
    u.x = f2bu(v.x); u.y = f2bu(v.y); u.z = f2bu(v.z); u.w = f2bu(v.w);
    *reinterpret_cast<ushort4*>(dst + (size_t)seg * ((size_t)DD * INNER_) + i) = u;
}

// transpose + convert: out[n][k] = bf16(in[k][n]); in [R][Cin] f32, out [Nout][R] bf16.
__global__ __launch_bounds__(256) void transpose_conv(
    const float* __restrict__ in, unsigned short* __restrict__ out,
    int R, int Cin, int Nout)
{
    __shared__ float t[32][33];
    int k0 = blockIdx.x * 32, n0 = blockIdx.y * 32;
#pragma unroll
    for (int i = 0; i < 4; ++i) {
        int k = k0 + threadIdx.y + i * 8;
        int n = n0 + threadIdx.x;
        t[threadIdx.y + i * 8][threadIdx.x] = (n < Cin) ? in[(size_t)k * Cin + n] : 0.f;
    }
    __syncthreads();
#pragma unroll
    for (int i = 0; i < 4; ++i) {
        int n = n0 + threadIdx.y + i * 8;
        int k = k0 + threadIdx.x;
        out[(size_t)n * R + k] = f2bu(t[threadIdx.x][threadIdx.y + i * 8]);
    }
}

// ---------------- bf16 MFMA GEMM (BT form, z-batched, BK=64) ----------------
// C[M,N] = alpha * A[M,K] * B[N,K]^T. A,B bf16 row-major, K-contiguous.
// 128x128 tile, BK=64, 4 waves, global_load_lds with 8-slot XOR swizzle.
// Unified z-decode: kidx = z & (SPLITK-1); zfull = z >> log2(SPLITK);
//   zb = zfull>>zs, zh = zfull & ((1<<zs)-1); offsets zb*s?b + zh*s?h;
//   K-chunk = kidx (K/SPLITK per chunk, must be %64).
// STORE: 0 = bf16 C (+czoff); 1 = bf16 C^T (C[c*ldc+r], packed 8B, +czoff);
//        2 = fp32 C + bias + rowmap + col guard; 3 = fp32 atomicAdd (+czoff);
//        4 = bf16 C with bias + exact GELU; 5 = fp32 C plain;
//        6 = masked exp -> bf16 C + shfl row-sum into bias=rsum[zfull*M+row]
//            (rowmap = uchar mask per batch zfull>>zs);
//        8 = fp32 plain store scaled by 1/bias[zfull*M + row], per-K-chunk
//            disjoint buffer: czoff += kidx * 16*M*ldc (16 = zfull count).
template<int STORE, int SPLITK>
__global__ __launch_bounds__(256) void gemm_bt(
    const unsigned short* __restrict__ A, int lda,
    const unsigned short* __restrict__ B, int ldb,
    void* __restrict__ Cv, int ldc,
    int M, int N, int K, float alpha, int zs,
    long long sAb, long long sAh, long long sBb, long long sBh,
    long long sCb, long long sCh,
    const float* __restrict__ bias, const int* __restrict__ rowmap)
{
    __shared__ unsigned short As[8192];  // 128 rows x 64 k (16 KB), slot-swizzled
    __shared__ unsigned short Bs[8192];
    const int tid = threadIdx.x;
    const int w = tid >> 6, l = tid & 63;
    const int m0 = blockIdx.x * 128, n0 = blockIdx.y * 128;

    constexpr int KSH = (SPLITK == 8) ? 3 : (SPLITK == 4) ? 2 : (SPLITK == 2) ? 1 : 0;
    const int kidx = blockIdx.z & (SPLITK - 1);
    const int zfull = blockIdx.z >> KSH;
    const int zb = zfull >> zs;
    const int zh = zfull - (zb << zs);
    const int kc = K / SPLITK;
    const int kbeg = kidx * kc, kend = kbeg + kc;
    A += zb * sAb + zh * sAh;
    B += zb * sBb + zh * sBh;
    const long long czoff = zb * sCb + zh * sCh;

    const int wr = (w >> 1) << 6, wc = (w & 1) << 6;
    const int lrow = l & 15, lk = l >> 4;

    // staging: round j writes LDS byte j*4096 + w*1024 + l*16.
    // row = off>>7 = j*32 + w*8 + (l>>3); lds slot = l&7;
    // global slot = (l&7) ^ (row&7) = (l&7) ^ (l>>3)
    const int sro = (w << 3) + (l >> 3);
    const int sko = (((l & 7) ^ (l >> 3)) << 3);
    const int ldst = (w << 10) + (l << 4);

    f32x4 acc[4][4];
#pragma unroll
    for (int mi = 0; mi < 4; ++mi)
#pragma unroll
        for (int ni = 0; ni < 4; ++ni)
            acc[mi][ni] = (f32x4){0.f, 0.f, 0.f, 0.f};

    for (int kt = kbeg; kt < kend; kt += 64) {
#pragma unroll
        for (int j = 0; j < 4; ++j)
            gload16(A + (size_t)(m0 + sro + j * 32) * lda + kt + sko,
                    (char*)As + (j << 12) + ldst);
#pragma unroll
        for (int j = 0; j < 4; ++j)
            gload16(B + (size_t)(n0 + sro + j * 32) * ldb + kt + sko,
                    (char*)Bs + (j << 12) + ldst);
        __syncthreads();

#pragma unroll
        for (int kk = 0; kk < 2; ++kk) {
            const int slot = (kk << 2) + lk;
            bf16x8 af[4], bfr[4];
#pragma unroll
            for (int mi = 0; mi < 4; ++mi) {
                int ra = wr + (mi << 4) + lrow;
                af[mi] = *reinterpret_cast<const bf16x8*>(
                    (const char*)As + (ra << 7) + ((slot ^ (ra & 7)) << 4));
            }
#pragma unroll
            for (int ni = 0; ni < 4; ++ni) {
                int rb = wc + (ni << 4) + lrow;
                bfr[ni] = *reinterpret_cast<const bf16x8*>(
                    (const char*)Bs + (rb << 7) + ((slot ^ (rb & 7)) << 4));
            }
#pragma unroll
            for (int mi = 0; mi < 4; ++mi)
#pragma unroll
                for (int ni = 0; ni < 4; ++ni)
                    acc[mi][ni] = __builtin_amdgcn_mfma_f32_16x16x32_bf16(
                        af[mi], bfr[ni], acc[mi][ni], 0, 0, 0);
        }
        __syncthreads();
    }

    // C/D layout: col = lane&15, row = (lane>>4)*4 + reg
    if (STORE == 0) {
        unsigned short* C = (unsigned short*)Cv + czoff;
#pragma unroll
        for (int mi = 0; mi < 4; ++mi) {
            int r = m0 + wr + (mi << 4) + (lk << 2);
#pragma unroll
            for (int ni = 0; ni < 4; ++ni) {
                int c = n0 + wc + (ni << 4) + lrow;
#pragma unroll
                for (int q = 0; q < 4; ++q)
                    C[(size_t)(r + q) * ldc + c] = f2bu(acc[mi][ni][q] * alpha);
            }
        }
    } else if (STORE == 1) {
        unsigned short* C = (unsigned short*)Cv + czoff;
#pragma unroll
        for (int ni = 0; ni < 4; ++ni) {
            int c = n0 + wc + (ni << 4) + lrow;
#pragma unroll
            for (int mi = 0; mi < 4; ++mi) {
                int r = m0 + wr + (mi << 4) + (lk << 2);
                ushort4 u;
                u.x = f2bu(acc[mi][ni][0] * alpha);
                u.y = f2bu(acc[mi][ni][1] * alpha);
                u.z = f2bu(acc[mi][ni][2] * alpha);
                u.w = f2bu(acc[mi][ni][3] * alpha);
                *reinterpret_cast<ushort4*>(&C[(size_t)c * ldc + r]) = u;
            }
        }
    } else if (STORE == 2) {
        float* C = (float*)Cv;
#pragma unroll
        for (int mi = 0; mi < 4; ++mi) {
            int r = m0 + wr + (mi << 4) + (lk << 2);
#pragma unroll
            for (int q = 0; q < 4; ++q) {
                int rm = rowmap[r + q];
                if (rm < 0) continue;
#pragma unroll
                for (int ni = 0; ni < 4; ++ni) {
                    int c = n0 + wc + (ni << 4) + lrow;
                    if (c < N) C[(size_t)rm * ldc + c] = acc[mi][ni][q] * alpha + bias[c];
                }
            }
        }
    } else if (STORE == 3) {
        float* C = (float*)Cv + czoff;
#pragma unroll
        for (int mi = 0; mi < 4; ++mi) {
            int r = m0 + wr + (mi << 4) + (lk << 2);
#pragma unroll
            for (int ni = 0; ni < 4; ++ni) {
                int c = n0 + wc + (ni << 4) + lrow;
#pragma unroll
                for (int q = 0; q < 4; ++q)
                    atomicAdd(&C[(size_t)(r + q) * ldc + c], acc[mi][ni][q] * alpha);
            }
        }
    } else if (STORE == 4) {
        unsigned short* C = (unsigned short*)Cv + czoff;
#pragma unroll
        for (int mi = 0; mi < 4; ++mi) {
            int r = m0 + wr + (mi << 4) + (lk << 2);
#pragma unroll
            for (int ni = 0; ni < 4; ++ni) {
                int c = n0 + wc + (ni << 4) + lrow;
#pragma unroll
                for (int q = 0; q < 4; ++q) {
                    float v = acc[mi][ni][q] * alpha + bias[c];
                    v = 0.5f * v * (1.f + erff(v * 0.70710678118f));
                    C[(size_t)(r + q) * ldc + c] = f2bu(v);
                }
            }
        }
    } else if (STORE == 5) {
        float* C = (float*)Cv + czoff;
#pragma unroll
        for (int mi = 0; mi < 4; ++mi) {
            int r = m0 + wr + (mi << 4) + (lk << 2);
#pragma unroll
            for (int ni = 0; ni < 4; ++ni) {
                int c = n0 + wc + (ni << 4) + lrow;
#pragma unroll
                for (int q = 0; q < 4; ++q)
                    C[(size_t)(r + q) * ldc + c] = acc[mi][ni][q] * alpha;
            }
        }
    } else if (STORE == 6) {
        // masked exp -> bf16 + per-row sum via shfl reduce (one atomic per segment)
        unsigned short* C = (unsigned short*)Cv + czoff;
        const unsigned char* mrow =
            (const unsigned char*)rowmap + (size_t)(zfull >> zs) * N;
        float* rsum = (float*)bias;
        float rpart[4][4];
#pragma unroll
        for (int mi = 0; mi < 4; ++mi)
#pragma unroll
            for (int q = 0; q < 4; ++q) rpart[mi][q] = 0.f;
#pragma unroll
        for (int mi = 0; mi < 4; ++mi) {
            int r = m0 + wr + (mi << 4) + (lk << 2);
#pragma unroll
            for (int ni = 0; ni < 4; ++ni) {
                int c = n0 + wc + (ni << 4) + lrow;
                bool msk = mrow[c] != 0;
#pragma unroll
                for (int q = 0; q < 4; ++q) {
                    float e = msk ? 0.f : expf(acc[mi][ni][q] * alpha);
                    C[(size_t)(r + q) * ldc + c] = f2bu(e);
                    rpart[mi][q] += e;
                }
            }
        }
        // reduce over the 16 lrow lanes (lanes sharing a row have the same lk)
#pragma unroll
        for (int mi = 0; mi < 4; ++mi)
#pragma unroll
            for (int q = 0; q < 4; ++q) {
                float s = rpart[mi][q];
                s += __shfl_xor(s, 1);
                s += __shfl_xor(s, 2);
                s += __shfl_xor(s, 4);
                s += __shfl_xor(s, 8);
                if (lrow == 0) {
                    int r = m0 + wr + (mi << 4) + (lk << 2) + q;
                    atomicAdd(&rsum[(size_t)zfull * M + r], s);
                }
            }
    } else {
        // STORE == 8: plain fp32 store scaled by 1/rowsum; K-chunks write
        // disjoint buffers (chunk stride = 16 zfull slices of M*ldc).
        float* C = (float*)Cv + czoff + (size_t)kidx * ((size_t)16 * M * ldc);
#pragma unroll
        for (int mi = 0; mi < 4; ++mi) {
            int r = m0 + wr + (mi << 4) + (lk << 2);
#pragma unroll
            for (int q = 0; q < 4; ++q) {
                float rinv = 1.f / bias[(size_t)zfull * M + r + q];
#pragma unroll
                for (int ni = 0; ni < 4; ++ni) {
                    int c = n0 + wc + (ni << 4) + lrow;
                    C[(size_t)(r + q) * ldc + c] = acc[mi][ni][q] * rinv;
                }
            }
        }
    }
}

// ---------------- residual + 16-slice sum + LayerNorm (emits bf16 copy) ----------------
// Oh has 32 slices of [1536][256]: slice (k*16 + b*8 + h), k = K-chunk 0..1.
__global__ __launch_bounds__(256) void ln8_kernel(
    float* __restrict__ x, const float* __restrict__ Oh,
    const float* __restrict__ abias,
    const float* __restrict__ g, const float* __restrict__ be,
    unsigned short* __restrict__ xb)
{
    __shared__ float red[4];
    const int r = blockIdx.x;
    const int b = (r >= 1536) ? 1 : 0;
    const int t = r - b * 1536;
    const int d = threadIdx.x;
    const long long idx = (long long)r * DD + d;
    float v = x[idx] + abias[d];
    const float* op = Oh + ((size_t)b * 8 * 1536 + t) * 256 + d;
    const size_t S = (size_t)1536 * 256;
#pragma unroll
    for (int h = 0; h < 8; ++h) v += op[h * S] + op[(16 + h) * S];

    float s = v;
#pragma unroll
    for (int off = 32; off > 0; off >>= 1) s += __shfl_down(s, off);
    if ((d & 63) == 0) red[d >> 6] = s;
    __syncthreads();
    float mean = (red[0] + red[1] + red[2] + red[3]) * (1.f / DD);
    __syncthreads();

    float df = v - mean;
    float s2 = df * df;
#pragma unroll
    for (int off = 32; off > 0; off >>= 1) s2 += __shfl_down(s2, off);
    if ((d & 63) == 0) red[d >> 6] = s2;
    __syncthreads();
    float var = (red[0] + red[1] + red[2] + red[3]) * (1.f / DD);

    float o = df / sqrtf(var + 1e-5f) * g[d] + be[d];
    x[idx] = o;
    xb[idx] = f2bu(o);
}

// ---------------- residual + LayerNorm (FFN path) ----------------
__global__ __launch_bounds__(256) void ln_kernel(
    float* __restrict__ x, const float* __restrict__ a,
    const float* __restrict__ abias,
    const float* __restrict__ g, const float* __restrict__ be,
    unsigned short* __restrict__ xb)
{
    __shared__ float red[4];
    const long long r = blockIdx.x;
    const int d = threadIdx.x;
    const long long idx = r * DD + d;
    float v = x[idx] + a[idx];
    if (abias) v += abias[d];

    float s = v;
#pragma unroll
    for (int off = 32; off > 0; off >>= 1) s += __shfl_down(s, off);
    if ((d & 63) == 0) red[d >> 6] = s;
    __syncthreads();
    float mean = (red[0] + red[1] + red[2] + red[3]) * (1.f / DD);
    __syncthreads();

    float df = v - mean;
    float s2 = df * df;
#pragma unroll
    for (int off = 32; off > 0; off >>= 1) s2 += __shfl_down(s2, off);
    if ((d & 63) == 0) red[d >> 6] = s2;
    __syncthreads();
    float var = (red[0] + red[1] + red[2] + red[3]) * (1.f / DD);

    float o = df / sqrtf(var + 1e-5f) * g[d] + be[d];
    x[idx] = o;
    xb[idx] = f2bu(o);
}

// ---------------- launch ----------------
extern "C" void kernel_launch(void* const* d_in, const int* in_sizes, int n_in,
                              void* d_out, int out_size, void* d_ws, size_t ws_size,
                              hipStream_t stream)
{
    const int*   src_ids = (const int*)d_in[0];
    const int*   t1      = (const int*)d_in[1];
    const int*   t2      = (const int*)d_in[2];
    const float* enc  = (const float*)d_in[4];
    const float* emb  = (const float*)d_in[5];
    const float* Wq_s = (const float*)d_in[6];
    const float* Wk_s = (const float*)d_in[7];
    const float* Wv_s = (const float*)d_in[8];
    const float* Wo_s = (const float*)d_in[9];
    const float* bo_s = (const float*)d_in[10];
    const float* Wq_c = (const float*)d_in[11];
    const float* Wk_c = (const float*)d_in[12];
    const float* Wv_c = (const float*)d_in[13];
    const float* Wo_c = (const float*)d_in[14];
    const float* bo_c = (const float*)d_in[15];
    const float* W1   = (const float*)d_in[16];
    const float* b1   = (const float*)d_in[17];
    const float* W2   = (const float*)d_in[18];
    const float* b2   = (const float*)d_in[19];
    const float* g1   = (const float*)d_in[20];
    const float* g2v  = (const float*)d_in[21];
    const float* g3   = (const float*)d_in[22];
    const float* be1  = (const float*)d_in[23];
    const float* be2  = (const float*)d_in[24];
    const float* be3  = (const float*)d_in[25];
    const float* Wfc  = (const float*)d_in[26];
    const float* bfc  = (const float*)d_in[27];

    // ---------------- d_ws layout (~85 MB) ----------------
    char* p = (char*)d_ws;
    float* x    = (float*)p;           p += (size_t)ROWS * DD * 4;
    float* aout = (float*)p;           p += (size_t)ROWS * DD * 4;
    float* rsum = (float*)p;           p += (size_t)32 * TT * 4;  // self [0..16TT), cross [16TT..32TT)
    unsigned short* h1b  = (unsigned short*)p; p += (size_t)ROWS * DD * 2;
    unsigned short* xb   = (unsigned short*)p; p += (size_t)ROWS * DD * 2;
    unsigned short* encb = (unsigned short*)p; p += (size_t)SROWS * DD * 2;
    unsigned short* Wqb_s = (unsigned short*)p; p += (size_t)DD * INNER_ * 2;  // 8 contiguous
    unsigned short* Wkb_s = (unsigned short*)p; p += (size_t)DD * INNER_ * 2;
    unsigned short* Wvb_s = (unsigned short*)p; p += (size_t)DD * INNER_ * 2;
    unsigned short* Wqb_c = (unsigned short*)p; p += (size_t)DD * INNER_ * 2;
    unsigned short* Wkb_c = (unsigned short*)p; p += (size_t)DD * INNER_ * 2;
    unsigned short* Wvb_c = (unsigned short*)p; p += (size_t)DD * INNER_ * 2;
    unsigned short* WoTs  = (unsigned short*)p; p += (size_t)DD * INNER_ * 2;
    unsigned short* WoTc  = (unsigned short*)p; p += (size_t)DD * INNER_ * 2;
    unsigned short* WfcT  = (unsigned short*)p; p += (size_t)VPAD * DD * 2;
    unsigned short* W1Tb  = (unsigned short*)p; p += (size_t)DD * DD * 2;
    unsigned short* W2Tb  = (unsigned short*)p; p += (size_t)DD * DD * 2;
    unsigned short* MtNb  = (unsigned short*)p; p += (size_t)4 * 524288 * 2;
    unsigned char* tgtpad = (unsigned char*)p; p += ROWS;
    unsigned char* srcpad = (unsigned char*)p; p += SROWS;
    p = (char*)(((size_t)p + 15) & ~(size_t)15);
    int* rowmap = (int*)p;             p += (size_t)ROWS * 4;

    float* rsumC = rsum + (size_t)16 * TT;

    unsigned short* Mtb_s = MtNb;
    unsigned short* Ntb_s = MtNb + 524288;
    unsigned short* Mtb_c = MtNb + 2 * 524288;
    unsigned short* Ntb_c = MtNb + 3 * 524288;

    // ---------------- d_out scratch (151 MB < 312 MB, dead before logits) ----
    unsigned short* ob = (unsigned short*)d_out;
    unsigned short* simS = ob;                    // [16][1536][1536] max (75.5 MB)
    unsigned short* Pb   = ob + 37748736;         // [8][3072][256]   (12.6 MB)
    unsigned short* YTb  = Pb + 6291456;          // [8][256][3072]   (12.6 MB)
    float* Oh = (float*)((char*)d_out + 100663296); // [32][1536][256] f32 (50.3 MB)
    float* MNacc = (float*)d_out;                 // [4][524288] f32, aliases simS (dead early)

    const long long WBLK = 4194304;  // one weight block (DD*INNER_) in elems

    // ---------------- prep ----------------
    embed_kernel<<<dim3(TT, BB), 256, 0, stream>>>(t1, t2, emb, x, xb, tgtpad);
    masks_kernel<<<dim3(ROWS / 256), 256, 0, stream>>>(src_ids, srcpad, rowmap);
    conv_bf16v4<<<dim3((SROWS * DD) / 1024), 256, 0, stream>>>(enc, encb);

    dim3 tcb(32, 8);
    convW6<<<dim3((DD * INNER_) / 1024, 6), 256, 0, stream>>>(
        Wq_s, Wk_s, Wv_s, Wq_c, Wk_c, Wv_c, Wqb_s);
    transpose_conv<<<dim3(512, 8), tcb, 0, stream>>>(Wo_s, WoTs, INNER_, DD, DD);
    transpose_conv<<<dim3(512, 8), tcb, 0, stream>>>(Wo_c, WoTc, INNER_, DD, DD);
    transpose_conv<<<dim3(8, VPAD / 32), tcb, 0, stream>>>(Wfc, WfcT, DD, VV, VPAD);
    transpose_conv<<<dim3(8, 8), tcb, 0, stream>>>(W1, W1Tb, DD, DD, DD);
    transpose_conv<<<dim3(8, 8), tcb, 0, stream>>>(W2, W2Tb, DD, DD, DD);

    const float scale = 0.022097086912079608f;  // DH^-0.5
    const long long Z0 = 0;

    // ---------------- M/N precompute (rank-256 folding), 2 merged launches ----
    hipMemsetAsync(MNacc, 0, (size_t)4 * 524288 * 4, stream);
    hipMemsetAsync(rsum, 0, (size_t)32 * TT * 4, stream);
    gemm_bt<3, 4><<<dim3(2, 2, 64), 256, 0, stream>>>(
        Wkb_s, INNER_, Wqb_s, INNER_, MNacc, 256, 256, 256, DHD, 1.f, 3,
        3 * WBLK, 2048, 3 * WBLK, 2048, 2 * 524288, 65536, nullptr, nullptr);
    gemm_bt<3, 4><<<dim3(2, 2, 64), 256, 0, stream>>>(
        WoTs, INNER_, Wvb_s, INNER_, MNacc + 524288, 2048, 256, 256, DHD, 1.f, 3,
        WBLK, 2048, 3 * WBLK, 2048, 2 * 524288, 256, nullptr, nullptr);
    conv_bf16v4<<<dim3((4 * 524288) / 1024), 256, 0, stream>>>(MNacc, MtNb);

    // ---------------- self attention ----------------
    // P_h = x @ Mt_h^T : [8][3072][256]
    gemm_bt<0, 1><<<dim3(24, 2, 8), 256, 0, stream>>>(
        xb, DD, Mtb_s, DD, Pb, DD, ROWS, DD, DD, 1.f, 3,
        Z0, Z0, Z0, 65536, Z0, 786432, nullptr, nullptr);
    // Y_h = x @ N_h, stored transposed: YT[8][256][3072]
    gemm_bt<1, 1><<<dim3(24, 2, 8), 256, 0, stream>>>(
        xb, DD, Ntb_s, 2048, YTb, ROWS, ROWS, DD, DD, 1.f, 3,
        Z0, Z0, Z0, 256, Z0, 786432, nullptr, nullptr);
    // expS = exp(scale * P_h @ x^T) masked; row sums into rsum (shfl epilogue)
    gemm_bt<6, 1><<<dim3(12, 12, 16), 256, 0, stream>>>(
        Pb, DD, xb, DD, simS, TT, TT, TT, DD, scale, 3,
        393216, 786432, 393216, Z0,
        18874368, 2359296, (const float*)rsum, (const int*)tgtpad);
    // Oh[k][z] = (expS/rowsum) @ Y_h : split-K=2, disjoint chunk buffers
    gemm_bt<8, 2><<<dim3(12, 2, 32), 256, 0, stream>>>(
        simS, TT, YTb, ROWS, Oh, DD, TT, DD, TT, 1.f, 3,
        18874368, 2359296, 1536, 786432,
        3145728, 393216, rsum, nullptr);
    ln8_kernel<<<dim3(ROWS), 256, 0, stream>>>(x, Oh, bo_s, g1, be1, xb);

    // ---------------- cross attention ----------------
    gemm_bt<0, 1><<<dim3(24, 2, 8), 256, 0, stream>>>(
        xb, DD, Mtb_c, DD, Pb, DD, ROWS, DD, DD, 1.f, 3,
        Z0, Z0, Z0, 65536, Z0, 786432, nullptr, nullptr);
    // Y_h = enc @ N_h, transposed: YT[8][256][2048]
    gemm_bt<1, 1><<<dim3(16, 2, 8), 256, 0, stream>>>(
        encb, DD, Ntb_c, 2048, YTb, SROWS, SROWS, DD, DD, 1.f, 3,
        Z0, Z0, Z0, 256, Z0, 524288, nullptr, nullptr);
    gemm_bt<6, 1><<<dim3(12, 8, 16), 256, 0, stream>>>(
        Pb, DD, encb, DD, simS, SS, TT, SS, DD, scale, 3,
        393216, 786432, 262144, Z0,
        12582912, 1572864, (const float*)rsumC, (const int*)srcpad);
    gemm_bt<8, 2><<<dim3(12, 2, 32), 256, 0, stream>>>(
        simS, SS, YTb, SROWS, Oh, DD, TT, DD, SS, 1.f, 3,
        12582912, 1572864, 1024, 524288,
        3145728, 393216, rsumC, nullptr);
    ln8_kernel<<<dim3(ROWS), 256, 0, stream>>>(x, Oh, bo_c, g2v, be2, xb);

    // ---------------- FFN (D->D->D, exact GELU), bf16 MFMA ----------------
    gemm_bt<4, 1><<<dim3(24, 2, 1), 256, 0, stream>>>(
        xb, DD, W1Tb, DD, h1b, DD, ROWS, DD, DD, 1.f, 0,
        Z0, Z0, Z0, Z0, Z0, Z0, b1, nullptr);
    gemm_bt<5, 1><<<dim3(24, 2, 1), 256, 0, stream>>>(
        h1b, DD, W2Tb, DD, aout, DD, ROWS, DD, DD, 1.f, 0,
        Z0, Z0, Z0, Z0, Z0, Z0, nullptr, nullptr);
    ln_kernel<<<dim3(ROWS), 256, 0, stream>>>(x, aout, b2, g3, be3, xb);

    // ---------------- logits (bf16 MFMA, rowmap drops t==0 rows) ----------------
    gemm_bt<2, 1><<<dim3(24, VPAD / 128, 1), 256, 0, stream>>>(
        xb, DD, WfcT, DD, d_out, VV, ROWS, VV, DD, 1.f, 0,
        Z0, Z0, Z0, Z0, Z0, Z0, bfc, rowmap);

    // ---------------- second output: x[:,0,:] ----------------
    copycls_kernel<<<dim3(BB), 256, 0, stream>>>(
        x, (float*)d_out + (long long)BB * (TT - 1) * VV);
}

// Round 17
// 543.601 us; speedup vs baseline: 1.0320x; 1.0320x over previous
//
#include <hip/hip_runtime.h>
#include <hip/hip_bf16.h>
#include <float.h>
#include <math.h>

// ---------------- problem constants ----------------
#define BB 2
#define SS 1024
#define LL 767
#define TT 1536          // 2*(LL+1)
#define DD 256
#define HH 8
#define DHD 2048
#define INNER_ 16384
#define VV 25426
#define VPAD 25472
#define CLS_TOK 25426
#define MASK_TOKEN 25428
#define ROWS (BB*TT)     // 3072
#define SROWS (BB*SS)    // 2048

typedef __attribute__((ext_vector_type(8))) __bf16 bf16x8;
typedef __attribute__((ext_vector_type(4))) float f32x4;

__device__ __forceinline__ unsigned short f2bu(float f) {
    union { float f; unsigned u; } v; v.f = f;
    unsigned r = v.u + 0x7fff + ((v.u >> 16) & 1);
    return (unsigned short)(r >> 16);
}
__device__ __forceinline__ float bu2f(unsigned short u) {
    union { unsigned u; float f; } v; v.u = ((unsigned)u) << 16;
    return v.f;
}

__device__ __forceinline__ void gload16(const void* g, void* l) {
    __builtin_amdgcn_global_load_lds(
        (const __attribute__((address_space(1))) void*)g,
        (__attribute__((address_space(3))) void*)l, 16, 0, 0);
}

// ---------------- small helper kernels ----------------

__global__ __launch_bounds__(256) void embed_kernel(
    const int* __restrict__ t1, const int* __restrict__ t2,
    const float* __restrict__ emb, float* __restrict__ x,
    unsigned short* __restrict__ xb, unsigned char* __restrict__ tgt_pad)
{
    int t = blockIdx.x, b = blockIdx.y, d = threadIdx.x;
    int raw;
    if (t == 0)            raw = CLS_TOK;
    else if (t <= LL)      raw = t1[b * LL + (t - 1)];
    else if (t == LL + 1)  raw = CLS_TOK;
    else                   raw = t2[b * LL + (t - LL - 2)];
    int id = (raw == 0 || raw == MASK_TOKEN) ? MASK_TOKEN : raw;
    int i = d >> 1;
    float ang = (float)t * expf(-0.03597789208f * (float)(2 * i));
    float pe = (d & 1) ? cosf(ang) : sinf(ang);
    float val = 2.f * emb[(long long)id * DD + d] + pe;
    long long idx = ((long long)(b * TT + t)) * DD + d;
    x[idx] = val;
    xb[idx] = f2bu(val);
    if (d == 0) tgt_pad[b * TT + t] = (raw == 0) ? 1 : 0;
}

// src pad mask + rowmap in one launch (grid ROWS/256)
__global__ __launch_bounds__(256) void masks_kernel(
    const int* __restrict__ src, unsigned char* __restrict__ m, int* __restrict__ rm)
{
    int i = blockIdx.x * 256 + threadIdx.x;
    if (i < SROWS) m[i] = (src[i] == 0) ? 1 : 0;
    if (i < ROWS) {
        int b = i / TT, t = i % TT;
        rm[i] = (t == 0) ? -1 : (b * (TT - 1) + t - 1);
    }
}

__global__ __launch_bounds__(256) void copycls_kernel(
    const float* __restrict__ x, float* __restrict__ out2)
{
    int b = blockIdx.x, d = threadIdx.x;
    out2[b * DD + d] = x[(long long)b * TT * DD + d];
}

// vectorized f32 -> bf16 convert (4 elems/thread); n % 1024 == 0
__global__ __launch_bounds__(256) void conv_bf16v4(
    const float* __restrict__ in, unsigned short* __restrict__ out)
{
    size_t i = ((size_t)blockIdx.x * 256 + threadIdx.x) * 4;
    float4 v = *reinterpret_cast<const float4*>(in + i);
    ushort4 u;
    u.x = f2bu(v.x); u.y = f2bu(v.y); u.z = f2bu(v.z); u.w = f2bu(v.w);
    *reinterpret_cast<ushort4*>(out + i) = u;
}

// six weight matrices [DD][INNER_] f32 -> contiguous bf16 (one launch)
__global__ __launch_bounds__(256) void convW6(
    const float* __restrict__ w0, const float* __restrict__ w1,
    const float* __restrict__ w2, const float* __restrict__ w3,
    const float* __restrict__ w4, const float* __restrict__ w5,
    unsigned short* __restrict__ dst)
{
    int seg = blockIdx.y;
    const float* s = seg == 0 ? w0 : seg == 1 ? w1 : seg == 2 ? w2 :
                     seg == 3 ? w3 : seg == 4 ? w4 : w5;
    size_t i = ((size_t)blockIdx.x * 256 + threadIdx.x) * 4;
    float4 v = *reinterpret_cast<const float4*>(s + i);
    ushort4 u;
    u.x = f2bu(v.x); u.y = f2bu(v.y); u.z = f2bu(v.z); u.w = f2bu(v.w);
    *reinterpret_cast<ushort4*>(dst + (size_t)seg * ((size_t)DD * INNER_) + i) = u;
}

// transpose + convert: out[n][k] = bf16(in[k][n]); in [R][Cin] f32, out [Nout][R] bf16.
__global__ __launch_bounds__(256) void transpose_conv(
    const float* __restrict__ in, unsigned short* __restrict__ out,
    int R, int Cin, int Nout)
{
    __shared__ float t[32][33];
    int k0 = blockIdx.x * 32, n0 = blockIdx.y * 32;
#pragma unroll
    for (int i = 0; i < 4; ++i) {
        int k = k0 + threadIdx.y + i * 8;
        int n = n0 + threadIdx.x;
        t[threadIdx.y + i * 8][threadIdx.x] = (n < Cin) ? in[(size_t)k * Cin + n] : 0.f;
    }
    __syncthreads();
#pragma unroll
    for (int i = 0; i < 4; ++i) {
        int n = n0 + threadIdx.y + i * 8;
        int k = k0 + threadIdx.x;
        out[(size_t)n * R + k] = f2bu(t[threadIdx.x][threadIdx.y + i * 8]);
    }
}

// ---------------- bf16 MFMA GEMM (BT form, z-batched, BK=64) ----------------
// C[M,N] = alpha * A[M,K] * B[N,K]^T. A,B bf16 row-major, K-contiguous.
// 128x128 tile, BK=64, 4 waves, global_load_lds with 8-slot XOR swizzle.
// Unified z-decode: kidx = z & (SPLITK-1); zfull = z >> log2(SPLITK);
//   zb = zfull>>zs, zh = zfull & ((1<<zs)-1); offsets zb*s?b + zh*s?h;
//   K-chunk = kidx (K/SPLITK per chunk, must be %64).
// STORE: 0 = bf16 C (+czoff); 1 = bf16 C^T (C[c*ldc+r], packed 8B, +czoff);
//        2 = fp32 C + bias + rowmap + col guard; 3 = fp32 atomicAdd (+czoff);
//        4 = bf16 C with bias + exact GELU; 5 = fp32 C plain;
//        6 = masked exp -> bf16 C + shfl row-sum into bias=rsum[zfull*M+row]
//            (rowmap = uchar mask per batch zfull>>zs);
//        8 = fp32 plain store scaled by 1/bias[zfull*M + row] (+czoff).
template<int STORE, int SPLITK>
__global__ __launch_bounds__(256) void gemm_bt(
    const unsigned short* __restrict__ A, int lda,
    const unsigned short* __restrict__ B, int ldb,
    void* __restrict__ Cv, int ldc,
    int M, int N, int K, float alpha, int zs,
    long long sAb, long long sAh, long long sBb, long long sBh,
    long long sCb, long long sCh,
    const float* __restrict__ bias, const int* __restrict__ rowmap)
{
    __shared__ unsigned short As[8192];  // 128 rows x 64 k (16 KB), slot-swizzled
    __shared__ unsigned short Bs[8192];
    const int tid = threadIdx.x;
    const int w = tid >> 6, l = tid & 63;
    const int m0 = blockIdx.x * 128, n0 = blockIdx.y * 128;

    constexpr int KSH = (SPLITK == 8) ? 3 : (SPLITK == 4) ? 2 : (SPLITK == 2) ? 1 : 0;
    const int kidx = blockIdx.z & (SPLITK - 1);
    const int zfull = blockIdx.z >> KSH;
    const int zb = zfull >> zs;
    const int zh = zfull - (zb << zs);
    const int kc = K / SPLITK;
    const int kbeg = kidx * kc, kend = kbeg + kc;
    A += zb * sAb + zh * sAh;
    B += zb * sBb + zh * sBh;
    const long long czoff = zb * sCb + zh * sCh;

    const int wr = (w >> 1) << 6, wc = (w & 1) << 6;
    const int lrow = l & 15, lk = l >> 4;

    // staging: round j writes LDS byte j*4096 + w*1024 + l*16.
    // row = off>>7 = j*32 + w*8 + (l>>3); lds slot = l&7;
    // global slot = (l&7) ^ (row&7) = (l&7) ^ (l>>3)
    const int sro = (w << 3) + (l >> 3);
    const int sko = (((l & 7) ^ (l >> 3)) << 3);
    const int ldst = (w << 10) + (l << 4);

    f32x4 acc[4][4];
#pragma unroll
    for (int mi = 0; mi < 4; ++mi)
#pragma unroll
        for (int ni = 0; ni < 4; ++ni)
            acc[mi][ni] = (f32x4){0.f, 0.f, 0.f, 0.f};

    for (int kt = kbeg; kt < kend; kt += 64) {
#pragma unroll
        for (int j = 0; j < 4; ++j)
            gload16(A + (size_t)(m0 + sro + j * 32) * lda + kt + sko,
                    (char*)As + (j << 12) + ldst);
#pragma unroll
        for (int j = 0; j < 4; ++j)
            gload16(B + (size_t)(n0 + sro + j * 32) * ldb + kt + sko,
                    (char*)Bs + (j << 12) + ldst);
        __syncthreads();

#pragma unroll
        for (int kk = 0; kk < 2; ++kk) {
            const int slot = (kk << 2) + lk;
            bf16x8 af[4], bfr[4];
#pragma unroll
            for (int mi = 0; mi < 4; ++mi) {
                int ra = wr + (mi << 4) + lrow;
                af[mi] = *reinterpret_cast<const bf16x8*>(
                    (const char*)As + (ra << 7) + ((slot ^ (ra & 7)) << 4));
            }
#pragma unroll
            for (int ni = 0; ni < 4; ++ni) {
                int rb = wc + (ni << 4) + lrow;
                bfr[ni] = *reinterpret_cast<const bf16x8*>(
                    (const char*)Bs + (rb << 7) + ((slot ^ (rb & 7)) << 4));
            }
#pragma unroll
            for (int mi = 0; mi < 4; ++mi)
#pragma unroll
                for (int ni = 0; ni < 4; ++ni)
                    acc[mi][ni] = __builtin_amdgcn_mfma_f32_16x16x32_bf16(
                        af[mi], bfr[ni], acc[mi][ni], 0, 0, 0);
        }
        __syncthreads();
    }

    // C/D layout: col = lane&15, row = (lane>>4)*4 + reg
    if (STORE == 0) {
        unsigned short* C = (unsigned short*)Cv + czoff;
#pragma unroll
        for (int mi = 0; mi < 4; ++mi) {
            int r = m0 + wr + (mi << 4) + (lk << 2);
#pragma unroll
            for (int ni = 0; ni < 4; ++ni) {
                int c = n0 + wc + (ni << 4) + lrow;
#pragma unroll
                for (int q = 0; q < 4; ++q)
                    C[(size_t)(r + q) * ldc + c] = f2bu(acc[mi][ni][q] * alpha);
            }
        }
    } else if (STORE == 1) {
        unsigned short* C = (unsigned short*)Cv + czoff;
#pragma unroll
        for (int ni = 0; ni < 4; ++ni) {
            int c = n0 + wc + (ni << 4) + lrow;
#pragma unroll
            for (int mi = 0; mi < 4; ++mi) {
                int r = m0 + wr + (mi << 4) + (lk << 2);
                ushort4 u;
                u.x = f2bu(acc[mi][ni][0] * alpha);
                u.y = f2bu(acc[mi][ni][1] * alpha);
                u.z = f2bu(acc[mi][ni][2] * alpha);
                u.w = f2bu(acc[mi][ni][3] * alpha);
                *reinterpret_cast<ushort4*>(&C[(size_t)c * ldc + r]) = u;
            }
        }
    } else if (STORE == 2) {
        float* C = (float*)Cv;
#pragma unroll
        for (int mi = 0; mi < 4; ++mi) {
            int r = m0 + wr + (mi << 4) + (lk << 2);
#pragma unroll
            for (int q = 0; q < 4; ++q) {
                int rm = rowmap[r + q];
                if (rm < 0) continue;
#pragma unroll
                for (int ni = 0; ni < 4; ++ni) {
                    int c = n0 + wc + (ni << 4) + lrow;
                    if (c < N) C[(size_t)rm * ldc + c] = acc[mi][ni][q] * alpha + bias[c];
                }
            }
        }
    } else if (STORE == 3) {
        float* C = (float*)Cv + czoff;
#pragma unroll
        for (int mi = 0; mi < 4; ++mi) {
            int r = m0 + wr + (mi << 4) + (lk << 2);
#pragma unroll
            for (int ni = 0; ni < 4; ++ni) {
                int c = n0 + wc + (ni << 4) + lrow;
#pragma unroll
                for (int q = 0; q < 4; ++q)
                    atomicAdd(&C[(size_t)(r + q) * ldc + c], acc[mi][ni][q] * alpha);
            }
        }
    } else if (STORE == 4) {
        unsigned short* C = (unsigned short*)Cv + czoff;
#pragma unroll
        for (int mi = 0; mi < 4; ++mi) {
            int r = m0 + wr + (mi << 4) + (lk << 2);
#pragma unroll
            for (int ni = 0; ni < 4; ++ni) {
                int c = n0 + wc + (ni << 4) + lrow;
#pragma unroll
                for (int q = 0; q < 4; ++q) {
                    float v = acc[mi][ni][q] * alpha + bias[c];
                    v = 0.5f * v * (1.f + erff(v * 0.70710678118f));
                    C[(size_t)(r + q) * ldc + c] = f2bu(v);
                }
            }
        }
    } else if (STORE == 5) {
        float* C = (float*)Cv + czoff;
#pragma unroll
        for (int mi = 0; mi < 4; ++mi) {
            int r = m0 + wr + (mi << 4) + (lk << 2);
#pragma unroll
            for (int ni = 0; ni < 4; ++ni) {
                int c = n0 + wc + (ni << 4) + lrow;
#pragma unroll
                for (int q = 0; q < 4; ++q)
                    C[(size_t)(r + q) * ldc + c] = acc[mi][ni][q] * alpha;
            }
        }
    } else if (STORE == 6) {
        // masked exp -> bf16 + per-row sum via shfl reduce (one atomic per segment)
        unsigned short* C = (unsigned short*)Cv + czoff;
        const unsigned char* mrow =
            (const unsigned char*)rowmap + (size_t)(zfull >> zs) * N;
        float* rsum = (float*)bias;
        float rpart[4][4];
#pragma unroll
        for (int mi = 0; mi < 4; ++mi)
#pragma unroll
            for (int q = 0; q < 4; ++q) rpart[mi][q] = 0.f;
#pragma unroll
        for (int mi = 0; mi < 4; ++mi) {
            int r = m0 + wr + (mi << 4) + (lk << 2);
#pragma unroll
            for (int ni = 0; ni < 4; ++ni) {
                int c = n0 + wc + (ni << 4) + lrow;
                bool msk = mrow[c] != 0;
#pragma unroll
                for (int q = 0; q < 4; ++q) {
                    float e = msk ? 0.f : expf(acc[mi][ni][q] * alpha);
                    C[(size_t)(r + q) * ldc + c] = f2bu(e);
                    rpart[mi][q] += e;
                }
            }
        }
        // reduce over the 16 lrow lanes (lanes sharing a row have the same lk)
#pragma unroll
        for (int mi = 0; mi < 4; ++mi)
#pragma unroll
            for (int q = 0; q < 4; ++q) {
                float s = rpart[mi][q];
                s += __shfl_xor(s, 1);
                s += __shfl_xor(s, 2);
                s += __shfl_xor(s, 4);
                s += __shfl_xor(s, 8);
                if (lrow == 0) {
                    int r = m0 + wr + (mi << 4) + (lk << 2) + q;
                    atomicAdd(&rsum[(size_t)zfull * M + r], s);
                }
            }
    } else {
        // STORE == 8: plain fp32 store scaled by 1/rowsum (per-z disjoint output)
        float* C = (float*)Cv + czoff;
#pragma unroll
        for (int mi = 0; mi < 4; ++mi) {
            int r = m0 + wr + (mi << 4) + (lk << 2);
#pragma unroll
            for (int q = 0; q < 4; ++q) {
                float rinv = 1.f / bias[(size_t)zfull * M + r + q];
#pragma unroll
                for (int ni = 0; ni < 4; ++ni) {
                    int c = n0 + wc + (ni << 4) + lrow;
                    C[(size_t)(r + q) * ldc + c] = acc[mi][ni][q] * rinv;
                }
            }
        }
    }
}

// ---------------- residual + 8-head sum + LayerNorm (emits bf16 copy) ----------------
__global__ __launch_bounds__(256) void ln8_kernel(
    float* __restrict__ x, const float* __restrict__ Oh,
    const float* __restrict__ abias,
    const float* __restrict__ g, const float* __restrict__ be,
    unsigned short* __restrict__ xb)
{
    __shared__ float red[4];
    const int r = blockIdx.x;
    const int b = (r >= 1536) ? 1 : 0;
    const int t = r - b * 1536;
    const int d = threadIdx.x;
    const long long idx = (long long)r * DD + d;
    float v = x[idx] + abias[d];
    const float* op = Oh + ((size_t)b * 8 * 1536 + t) * 256 + d;
#pragma unroll
    for (int h = 0; h < 8; ++h) v += op[(size_t)h * 1536 * 256];

    float s = v;
#pragma unroll
    for (int off = 32; off > 0; off >>= 1) s += __shfl_down(s, off);
    if ((d & 63) == 0) red[d >> 6] = s;
    __syncthreads();
    float mean = (red[0] + red[1] + red[2] + red[3]) * (1.f / DD);
    __syncthreads();

    float df = v - mean;
    float s2 = df * df;
#pragma unroll
    for (int off = 32; off > 0; off >>= 1) s2 += __shfl_down(s2, off);
    if ((d & 63) == 0) red[d >> 6] = s2;
    __syncthreads();
    float var = (red[0] + red[1] + red[2] + red[3]) * (1.f / DD);

    float o = df / sqrtf(var + 1e-5f) * g[d] + be[d];
    x[idx] = o;
    xb[idx] = f2bu(o);
}

// ---------------- residual + LayerNorm (FFN path) ----------------
__global__ __launch_bounds__(256) void ln_kernel(
    float* __restrict__ x, const float* __restrict__ a,
    const float* __restrict__ abias,
    const float* __restrict__ g, const float* __restrict__ be,
    unsigned short* __restrict__ xb)
{
    __shared__ float red[4];
    const long long r = blockIdx.x;
    const int d = threadIdx.x;
    const long long idx = r * DD + d;
    float v = x[idx] + a[idx];
    if (abias) v += abias[d];

    float s = v;
#pragma unroll
    for (int off = 32; off > 0; off >>= 1) s += __shfl_down(s, off);
    if ((d & 63) == 0) red[d >> 6] = s;
    __syncthreads();
    float mean = (red[0] + red[1] + red[2] + red[3]) * (1.f / DD);
    __syncthreads();

    float df = v - mean;
    float s2 = df * df;
#pragma unroll
    for (int off = 32; off > 0; off >>= 1) s2 += __shfl_down(s2, off);
    if ((d & 63) == 0) red[d >> 6] = s2;
    __syncthreads();
    float var = (red[0] + red[1] + red[2] + red[3]) * (1.f / DD);

    float o = df / sqrtf(var + 1e-5f) * g[d] + be[d];
    x[idx] = o;
    xb[idx] = f2bu(o);
}

// ---------------- launch ----------------
extern "C" void kernel_launch(void* const* d_in, const int* in_sizes, int n_in,
                              void* d_out, int out_size, void* d_ws, size_t ws_size,
                              hipStream_t stream)
{
    const int*   src_ids = (const int*)d_in[0];
    const int*   t1      = (const int*)d_in[1];
    const int*   t2      = (const int*)d_in[2];
    const float* enc  = (const float*)d_in[4];
    const float* emb  = (const float*)d_in[5];
    const float* Wq_s = (const float*)d_in[6];
    const float* Wk_s = (const float*)d_in[7];
    const float* Wv_s = (const float*)d_in[8];
    const float* Wo_s = (const float*)d_in[9];
    const float* bo_s = (const float*)d_in[10];
    const float* Wq_c = (const float*)d_in[11];
    const float* Wk_c = (const float*)d_in[12];
    const float* Wv_c = (const float*)d_in[13];
    const float* Wo_c = (const float*)d_in[14];
    const float* bo_c = (const float*)d_in[15];
    const float* W1   = (const float*)d_in[16];
    const float* b1   = (const float*)d_in[17];
    const float* W2   = (const float*)d_in[18];
    const float* b2   = (const float*)d_in[19];
    const float* g1   = (const float*)d_in[20];
    const float* g2v  = (const float*)d_in[21];
    const float* g3   = (const float*)d_in[22];
    const float* be1  = (const float*)d_in[23];
    const float* be2  = (const float*)d_in[24];
    const float* be3  = (const float*)d_in[25];
    const float* Wfc  = (const float*)d_in[26];
    const float* bfc  = (const float*)d_in[27];

    // ---------------- d_ws layout (~85 MB) ----------------
    char* p = (char*)d_ws;
    float* x    = (float*)p;           p += (size_t)ROWS * DD * 4;
    float* aout = (float*)p;           p += (size_t)ROWS * DD * 4;
    float* rsum = (float*)p;           p += (size_t)16 * TT * 4;
    unsigned short* h1b  = (unsigned short*)p; p += (size_t)ROWS * DD * 2;
    unsigned short* xb   = (unsigned short*)p; p += (size_t)ROWS * DD * 2;
    unsigned short* encb = (unsigned short*)p; p += (size_t)SROWS * DD * 2;
    unsigned short* Wqb_s = (unsigned short*)p; p += (size_t)DD * INNER_ * 2;  // 8 contiguous
    unsigned short* Wkb_s = (unsigned short*)p; p += (size_t)DD * INNER_ * 2;
    unsigned short* Wvb_s = (unsigned short*)p; p += (size_t)DD * INNER_ * 2;
    unsigned short* Wqb_c = (unsigned short*)p; p += (size_t)DD * INNER_ * 2;
    unsigned short* Wkb_c = (unsigned short*)p; p += (size_t)DD * INNER_ * 2;
    unsigned short* Wvb_c = (unsigned short*)p; p += (size_t)DD * INNER_ * 2;
    unsigned short* WoTs  = (unsigned short*)p; p += (size_t)DD * INNER_ * 2;
    unsigned short* WoTc  = (unsigned short*)p; p += (size_t)DD * INNER_ * 2;
    unsigned short* WfcT  = (unsigned short*)p; p += (size_t)VPAD * DD * 2;
    unsigned short* W1Tb  = (unsigned short*)p; p += (size_t)DD * DD * 2;
    unsigned short* W2Tb  = (unsigned short*)p; p += (size_t)DD * DD * 2;
    unsigned short* MtNb  = (unsigned short*)p; p += (size_t)4 * 524288 * 2;
    unsigned char* tgtpad = (unsigned char*)p; p += ROWS;
    unsigned char* srcpad = (unsigned char*)p; p += SROWS;
    p = (char*)(((size_t)p + 15) & ~(size_t)15);
    int* rowmap = (int*)p;             p += (size_t)ROWS * 4;

    unsigned short* Mtb_s = MtNb;
    unsigned short* Ntb_s = MtNb + 524288;
    unsigned short* Mtb_c = MtNb + 2 * 524288;
    unsigned short* Ntb_c = MtNb + 3 * 524288;

    // ---------------- d_out scratch (125.8 MB < 312 MB, dead before logits) ----
    unsigned short* ob = (unsigned short*)d_out;
    unsigned short* simS = ob;                    // [16][1536][1536] max (75.5 MB)
    unsigned short* Pb   = ob + 37748736;         // [8][3072][256]   (12.6 MB)
    unsigned short* YTb  = Pb + 6291456;          // [8][256][3072]   (12.6 MB)
    float* Oh = (float*)((char*)d_out + 100663296); // [16][1536][256] f32 (25.2 MB)
    float* MNacc = (float*)d_out;                 // [4][524288] f32, aliases simS (dead early)

    const long long WBLK = 4194304;  // one weight block (DD*INNER_) in elems

    // ---------------- prep ----------------
    embed_kernel<<<dim3(TT, BB), 256, 0, stream>>>(t1, t2, emb, x, xb, tgtpad);
    masks_kernel<<<dim3(ROWS / 256), 256, 0, stream>>>(src_ids, srcpad, rowmap);
    conv_bf16v4<<<dim3((SROWS * DD) / 1024), 256, 0, stream>>>(enc, encb);

    dim3 tcb(32, 8);
    convW6<<<dim3((DD * INNER_) / 1024, 6), 256, 0, stream>>>(
        Wq_s, Wk_s, Wv_s, Wq_c, Wk_c, Wv_c, Wqb_s);
    transpose_conv<<<dim3(512, 8), tcb, 0, stream>>>(Wo_s, WoTs, INNER_, DD, DD);
    transpose_conv<<<dim3(512, 8), tcb, 0, stream>>>(Wo_c, WoTc, INNER_, DD, DD);
    transpose_conv<<<dim3(8, VPAD / 32), tcb, 0, stream>>>(Wfc, WfcT, DD, VV, VPAD);
    transpose_conv<<<dim3(8, 8), tcb, 0, stream>>>(W1, W1Tb, DD, DD, DD);
    transpose_conv<<<dim3(8, 8), tcb, 0, stream>>>(W2, W2Tb, DD, DD, DD);

    const float scale = 0.022097086912079608f;  // DH^-0.5
    const long long Z0 = 0;

    // ---------------- M/N precompute (rank-256 folding), 2 merged launches ----
    hipMemsetAsync(MNacc, 0, (size_t)4 * 524288 * 4, stream);
    gemm_bt<3, 4><<<dim3(2, 2, 64), 256, 0, stream>>>(
        Wkb_s, INNER_, Wqb_s, INNER_, MNacc, 256, 256, 256, DHD, 1.f, 3,
        3 * WBLK, 2048, 3 * WBLK, 2048, 2 * 524288, 65536, nullptr, nullptr);
    gemm_bt<3, 4><<<dim3(2, 2, 64), 256, 0, stream>>>(
        WoTs, INNER_, Wvb_s, INNER_, MNacc + 524288, 2048, 256, 256, DHD, 1.f, 3,
        WBLK, 2048, 3 * WBLK, 2048, 2 * 524288, 256, nullptr, nullptr);
    conv_bf16v4<<<dim3((4 * 524288) / 1024), 256, 0, stream>>>(MNacc, MtNb);

    // ---------------- self attention ----------------
    hipMemsetAsync(rsum, 0, (size_t)16 * TT * 4, stream);
    // P_h = x @ Mt_h^T : [8][3072][256]
    gemm_bt<0, 1><<<dim3(24, 2, 8), 256, 0, stream>>>(
        xb, DD, Mtb_s, DD, Pb, DD, ROWS, DD, DD, 1.f, 3,
        Z0, Z0, Z0, 65536, Z0, 786432, nullptr, nullptr);
    // Y_h = x @ N_h, stored transposed: YT[8][256][3072]
    gemm_bt<1, 1><<<dim3(24, 2, 8), 256, 0, stream>>>(
        xb, DD, Ntb_s, 2048, YTb, ROWS, ROWS, DD, DD, 1.f, 3,
        Z0, Z0, Z0, 256, Z0, 786432, nullptr, nullptr);
    // expS = exp(scale * P_h @ x^T) masked; row sums into rsum (shfl epilogue)
    gemm_bt<6, 1><<<dim3(12, 12, 16), 256, 0, stream>>>(
        Pb, DD, xb, DD, simS, TT, TT, TT, DD, scale, 3,
        393216, 786432, 393216, Z0,
        18874368, 2359296, (const float*)rsum, (const int*)tgtpad);
    // Oh[z] = (expS/rowsum) @ Y_h : plain per-head store (no atomics)
    gemm_bt<8, 1><<<dim3(12, 2, 16), 256, 0, stream>>>(
        simS, TT, YTb, ROWS, Oh, DD, TT, DD, TT, 1.f, 3,
        18874368, 2359296, 1536, 786432,
        3145728, 393216, rsum, nullptr);
    ln8_kernel<<<dim3(ROWS), 256, 0, stream>>>(x, Oh, bo_s, g1, be1, xb);

    // ---------------- cross attention ----------------
    hipMemsetAsync(rsum, 0, (size_t)16 * TT * 4, stream);
    gemm_bt<0, 1><<<dim3(24, 2, 8), 256, 0, stream>>>(
        xb, DD, Mtb_c, DD, Pb, DD, ROWS, DD, DD, 1.f, 3,
        Z0, Z0, Z0, 65536, Z0, 786432, nullptr, nullptr);
    // Y_h = enc @ N_h, transposed: YT[8][256][2048]
    gemm_bt<1, 1><<<dim3(16, 2, 8), 256, 0, stream>>>(
        encb, DD, Ntb_c, 2048, YTb, SROWS, SROWS, DD, DD, 1.f, 3,
        Z0, Z0, Z0, 256, Z0, 524288, nullptr, nullptr);
    gemm_bt<6, 1><<<dim3(12, 8, 16), 256, 0, stream>>>(
        Pb, DD, encb, DD, simS, SS, TT, SS, DD, scale, 3,
        393216, 786432, 262144, Z0,
        12582912, 1572864, (const float*)rsum, (const int*)srcpad);
    gemm_bt<8, 1><<<dim3(12, 2, 16), 256, 0, stream>>>(
        simS, SS, YTb, SROWS, Oh, DD, TT, DD, SS, 1.f, 3,
        12582912, 1572864, 1024, 524288,
        3145728, 393216, rsum, nullptr);
    ln8_kernel<<<dim3(ROWS), 256, 0, stream>>>(x, Oh, bo_c, g2v, be2, xb);

    // ---------------- FFN (D->D->D, exact GELU), bf16 MFMA ----------------
    gemm_bt<4, 1><<<dim3(24, 2, 1), 256, 0, stream>>>(
        xb, DD, W1Tb, DD, h1b, DD, ROWS, DD, DD, 1.f, 0,
        Z0, Z0, Z0, Z0, Z0, Z0, b1, nullptr);
    gemm_bt<5, 1><<<dim3(24, 2, 1), 256, 0, stream>>>(
        h1b, DD, W2Tb, DD, aout, DD, ROWS, DD, DD, 1.f, 0,
        Z0, Z0, Z0, Z0, Z0, Z0, nullptr, nullptr);
    ln_kernel<<<dim3(ROWS), 256, 0, stream>>>(x, aout, b2, g3, be3, xb);

    // ---------------- logits (bf16 MFMA, rowmap drops t==0 rows) ----------------
    gemm_bt<2, 1><<<dim3(24, VPAD / 128, 1), 256, 0, stream>>>(
        xb, DD, WfcT, DD, d_out, VV, ROWS, VV, DD, 1.f, 0,
        Z0, Z0, Z0, Z0, Z0, Z0, bfc, rowmap);

    // ---------------- second output: x[:,0,:] ----------------
    copycls_kernel<<<dim3(BB), 256, 0, stream>>>(
        x, (float*)d_out + (long long)BB * (TT - 1) * VV);
}